// Round 1
// baseline (2871.898 us; speedup 1.0000x reference)
//
#include <hip/hip_runtime.h>

#define T_LEN 4096
#define B_SZ  256

__device__ __forceinline__ float fexp2(float x) { return __builtin_amdgcn_exp2f(x); }
__device__ __forceinline__ float frcp(float x)  { return __builtin_amdgcn_rcpf(x); }

// ---------------------------------------------------------------------------
// Init: y1 <- bl1 broadcast, out <- bl2 broadcast (biases of the two linears).
// The recurrent kernels atomically add their projected h contributions on top.
// ---------------------------------------------------------------------------
__global__ void init_bias_kernel(const float* __restrict__ bl1,
                                 const float* __restrict__ bl2,
                                 float* __restrict__ y1,
                                 float* __restrict__ out)
{
    const long idx = (long)blockIdx.x * blockDim.x + threadIdx.x; // over B*T
    float4 a1 = make_float4(bl1[0], bl1[1], bl1[2], bl1[3]);
    float4 b1 = make_float4(bl1[4], bl1[5], bl1[6], bl1[7]);
    float4 a2 = make_float4(bl2[0], bl2[1], bl2[2], bl2[3]);
    float4 b2 = make_float4(bl2[4], bl2[5], bl2[6], bl2[7]);
    float4* y4 = (float4*)y1;
    float4* o4 = (float4*)out;
    y4[idx * 2 + 0] = a1;
    y4[idx * 2 + 1] = b1;
    o4[idx * 2 + 0] = a2;
    o4[idx * 2 + 1] = b2;
}

// ---------------------------------------------------------------------------
// One bidirectional LSTM layer + fused output projection.
// Cell (batch, dir) on 8 lanes; lane j = hidden unit j (owns gate rows
// {j, 8+j, 16+j, 24+j}, PyTorch order i,f,g,o). 8 cells/wave, 1 wave/block.
// Grid: 64 blocks x 64 threads. cells 0..255 = fwd, 256..511 = bwd
// (dir uniform per block). Weights pre-scaled by -log2(e) (sigmoid gates)
// or -2*log2(e) (tanh gate) so activations are rcp(1+exp2(z)).
// Output projection is lagged: at iter t the broadcast hb[] holds h_{t-1};
// lane j adds  sum_k hb[k]*W[j][dir*8+k]  into y[b][t-1][j] atomically.
// ---------------------------------------------------------------------------
__global__ __launch_bounds__(64, 1)
void lstm_layer_kernel(const float* __restrict__ x,     // [B,T,8]
                       const float* __restrict__ WihF, const float* __restrict__ WhhF,
                       const float* __restrict__ bF,
                       const float* __restrict__ WihB, const float* __restrict__ WhhB,
                       const float* __restrict__ bB,
                       const float* __restrict__ Wproj, // [8][16] (fwd cols 0..7, bwd 8..15)
                       float* __restrict__ y)           // [B,T,8], pre-inited with bias
{
    const int tid  = threadIdx.x;
    const int j    = tid & 7;
    const int cell = blockIdx.x * 8 + (tid >> 3);
    const int isB  = cell >> 8;          // uniform per block
    const int b    = cell & 255;

    const float* Wih  = isB ? WihB : WihF;
    const float* Whh  = isB ? WhhB : WhhF;
    const float* bias = isB ? bB   : bF;

    const float NL2E = -1.4426950408889634f;

    // Per-lane constant weights, pre-scaled for exp2-based activations.
    float Wi[4][8], Wh[4][8], bb[4], Wc[8];
    #pragma unroll
    for (int g = 0; g < 4; ++g) {
        const float s = (g == 2) ? (2.0f * NL2E) : NL2E;
        const int r = g * 8 + j;
        #pragma unroll
        for (int k = 0; k < 8; ++k) {
            Wi[g][k] = Wih[r * 8 + k] * s;
            Wh[g][k] = Whh[r * 8 + k] * s;
        }
        bb[g] = bias[r] * s;
    }
    #pragma unroll
    for (int k = 0; k < 8; ++k)
        Wc[k] = Wproj[j * 16 + isB * 8 + k];

    float c = 0.0f, h = 0.0f;
    const float4* x4 = (const float4*)x;

    for (int t = 0; t < T_LEN; ++t) {
        const int tt = isB ? (T_LEN - 1 - t) : t;
        const long base = (long)b * T_LEN + tt;

        // x_t (8 floats, shared by the cell's 8 lanes; L1 broadcast)
        float4 xa = x4[base * 2 + 0];
        float4 xb = x4[base * 2 + 1];
        float xv[8] = {xa.x, xa.y, xa.z, xa.w, xb.x, xb.y, xb.z, xb.w};

        // input projection (off the dependency chain)
        float acc[4];
        #pragma unroll
        for (int g = 0; g < 4; ++g) {
            float a = bb[g];
            #pragma unroll
            for (int k = 0; k < 8; ++k) a = fmaf(Wi[g][k], xv[k], a);
            acc[g] = a;
        }

        // broadcast previous h across the 8 lanes of the cell
        float hb[8];
        #pragma unroll
        for (int k = 0; k < 8; ++k) hb[k] = __shfl(h, k, 8);

        // fused output projection for step t-1 (hb holds h_{t-1})
        if (t > 0) {
            const int ptt = isB ? (tt + 1) : (tt - 1);
            float contrib = 0.0f;
            #pragma unroll
            for (int k = 0; k < 8; ++k) contrib = fmaf(hb[k], Wc[k], contrib);
            atomicAdd(&y[((long)b * T_LEN + ptt) * 8 + j], contrib);
        }

        // hidden projection
        #pragma unroll
        for (int g = 0; g < 4; ++g) {
            float a = acc[g];
            #pragma unroll
            for (int k = 0; k < 8; ++k) a = fmaf(Wh[g][k], hb[k], a);
            acc[g] = a;
        }

        // activations: z pre-scaled, so sigma(z) = rcp(1+exp2(zs)),
        // tanh(z) = 2*rcp(1+exp2(zs)) - 1
        const float si = frcp(1.0f + fexp2(acc[0]));
        const float sf = frcp(1.0f + fexp2(acc[1]));
        const float tg = 2.0f * frcp(1.0f + fexp2(acc[2])) - 1.0f;
        const float so = frcp(1.0f + fexp2(acc[3]));

        c = fmaf(sf, c, si * tg);
        const float ec = fexp2(2.0f * NL2E * c);
        const float th = 2.0f * frcp(1.0f + ec) - 1.0f;
        h = so * th;
    }

    // tail: contribution of the last computed h
    {
        float hb[8];
        #pragma unroll
        for (int k = 0; k < 8; ++k) hb[k] = __shfl(h, k, 8);
        const int ltt = isB ? 0 : (T_LEN - 1);
        float contrib = 0.0f;
        #pragma unroll
        for (int k = 0; k < 8; ++k) contrib = fmaf(hb[k], Wc[k], contrib);
        atomicAdd(&y[((long)b * T_LEN + ltt) * 8 + j], contrib);
    }
}

extern "C" void kernel_launch(void* const* d_in, const int* in_sizes, int n_in,
                              void* d_out, int out_size, void* d_ws, size_t ws_size,
                              hipStream_t stream)
{
    const float* x     = (const float*)d_in[0];
    const float* Wih1f = (const float*)d_in[1];
    const float* Whh1f = (const float*)d_in[2];
    const float* b1f   = (const float*)d_in[3];
    const float* Wih1b = (const float*)d_in[4];
    const float* Whh1b = (const float*)d_in[5];
    const float* b1b   = (const float*)d_in[6];
    const float* Wih2f = (const float*)d_in[7];
    const float* Whh2f = (const float*)d_in[8];
    const float* b2f   = (const float*)d_in[9];
    const float* Wih2b = (const float*)d_in[10];
    const float* Whh2b = (const float*)d_in[11];
    const float* b2b   = (const float*)d_in[12];
    const float* W1    = (const float*)d_in[13];
    const float* bl1   = (const float*)d_in[14];
    const float* W2    = (const float*)d_in[15];
    const float* bl2   = (const float*)d_in[16];

    float* out = (float*)d_out;
    float* y1  = (float*)d_ws;   // [B,T,8] fp32 = 32 MB

    const int BT = B_SZ * T_LEN; // 1,048,576

    // bias init for both fused linears
    init_bias_kernel<<<BT / 256, 256, 0, stream>>>(bl1, bl2, y1, out);

    // layer 1: x -> y1 (atomic-add fused projection through W1)
    lstm_layer_kernel<<<64, 64, 0, stream>>>(x, Wih1f, Whh1f, b1f,
                                             Wih1b, Whh1b, b1b, W1, y1);

    // layer 2: y1 -> out (fused projection through W2)
    lstm_layer_kernel<<<64, 64, 0, stream>>>(y1, Wih2f, Whh2f, b2f,
                                             Wih2b, Whh2b, b2b, W2, out);
}